// Round 7
// baseline (209.131 us; speedup 1.0000x reference)
//
#include <hip/hip_runtime.h>

typedef __bf16 bf16;
typedef __attribute__((ext_vector_type(8))) __bf16 bf16x8;
typedef __attribute__((ext_vector_type(4))) float f32x4;

union U16x8 { uint4 u; bf16 h[8]; };
union Pack4 { uint2 u2; bf16 h[4]; };

#define QSCALE 0.18033688011112042f   // log2(e)/sqrt(64)

__device__ __forceinline__ void async16(const bf16* g, bf16* l) {
    __builtin_amdgcn_global_load_lds((const __attribute__((address_space(1))) void*)g,
                                     (__attribute__((address_space(3))) void*)l, 16, 0, 0);
}
__device__ __forceinline__ void async4(const bf16* g, bf16* l) {
    __builtin_amdgcn_global_load_lds((const __attribute__((address_space(1))) void*)g,
                                     (__attribute__((address_space(3))) void*)l, 4, 0, 0);
}

// split-K item tables: 40 items per (b,h), ordered heaviest-first
__device__ const int QT_OF[40] = {15,15,15,15,14,14,14,14,13,13,13,13,12,12,12,12,
                                  11,11,11,10,10,10,9,9,9,8,8,8,7,7,6,6,5,5,4,4,3,2,1,0};
__device__ const int CK_OF[40] = {0,1,2,3,0,1,2,3,0,1,2,3,0,1,2,3,
                                  0,1,2,0,1,2,0,1,2,0,1,2,0,1,0,1,0,1,0,1,0,0,0,0};
__device__ const int BASE_OF[16] = {39,38,37,36,34,32,30,28,25,22,19,16,12,8,4,0};

// ---------------- prep: csum zero + fp32->bf16 convert + 3 weight transposes ----------------
__global__ void prep(const float* __restrict__ hs, bf16* __restrict__ hsb,
                     const float* __restrict__ qkw, const float* __restrict__ vw,
                     const float* __restrict__ pw, bf16* __restrict__ qkvT,
                     bf16* __restrict__ pwT, float* __restrict__ csum,
                     const float* __restrict__ vrg, const float* __restrict__ vsg,
                     const float* __restrict__ prg, const float* __restrict__ psg) {
    const int K = 1024;
    int bx = blockIdx.x;
    if (bx < 8) {
        float4* p = (float4*)csum + (bx * 256 + threadIdx.x) * 16;
        #pragma unroll
        for (int i = 0; i < 16; i++) p[i] = make_float4(0.f, 0.f, 0.f, 0.f);
        return;
    }
    if (bx < 4104) {
        int i = ((bx - 8) * 256 + threadIdx.x) * 4;
        float4 f = *(const float4*)(hs + i);
        hsb[i + 0] = (bf16)f.x; hsb[i + 1] = (bf16)f.y;
        hsb[i + 2] = (bf16)f.z; hsb[i + 3] = (bf16)f.w;
        return;
    }
    int r = bx - 4104;
    int z = r < 2048 ? 0 : (r < 3072 ? 1 : 2);
    int q = z == 0 ? r : (z == 1 ? r - 2048 : r - 3072);
    int ntiles = z == 0 ? 64 : 32;
    int N = z == 0 ? 2048 : 1024;
    const float* W = z == 0 ? qkw : (z == 1 ? vw : pw);
    bf16* WT = z == 0 ? qkvT : (z == 1 ? qkvT + (size_t)2 * 1024 * 1024 : pwT);
    float g0 = z == 0 ? 1.f : (z == 1 ? vrg[0] : prg[0]);
    float g1 = z == 0 ? 0.f : (z == 1 ? vsg[0] : psg[0]);

    __shared__ float tile[32][33];
    int n0 = (q % ntiles) * 32, k0 = (q / ntiles) * 32;
    int tx = threadIdx.x & 31, ty = threadIdx.x >> 5;
    #pragma unroll
    for (int rr = 0; rr < 32; rr += 8)
        tile[ty + rr][tx] = W[(size_t)(k0 + ty + rr) * N + n0 + tx];
    __syncthreads();
    #pragma unroll
    for (int rr = 0; rr < 32; rr += 8) {
        int n = n0 + ty + rr, k = k0 + tx;
        float v = g0 * tile[tx][ty + rr] + ((n == k) ? g1 : 0.f);
        if (z == 0 && n < 1024) v *= QSCALE;
        WT[(size_t)n * K + k] = (bf16)v;
    }
}

// ---------------- bf16 MFMA GEMM, XCD-swizzled 1D grid: C = A @ BT^T ----------------
// mode 0: fused qk+v. col<2048 -> qko (bias); col>=2048 -> vT (scatter) + csumT atomics
// mode 2: out fp32 = acc (gains pre-folded)
template<int BN>
__global__ __launch_bounds__(256, 3)
void gemm_bt(const bf16* __restrict__ A, const bf16* __restrict__ BT,
             int M, int N, int K, void* __restrict__ Cout,
             bf16* __restrict__ C2T, float* __restrict__ csum,
             int mode, const float* __restrict__ aux) {
    __shared__ __align__(16) bf16 As[128][64];
    __shared__ __align__(16) bf16 Bs[BN][64];
    constexpr int JF = BN / 32;
    int bid = blockIdx.x;
    int g32 = bid & 31;
    int m0 = ((g32 & 7) * 4 + (g32 >> 3)) * 128;
    int n0 = (bid >> 5) * BN;
    int t = threadIdx.x, lane = t & 63, w = t >> 6;
    int wm = (w >> 1) * 64, wn = (w & 1) * (BN / 2);
    int lrow = lane & 15, lkg = lane >> 4;

    f32x4 acc[4][JF] = {};

    int gsw = ((lane & 7) ^ ((lane >> 3) & 7)) * 8;
    const bf16* Ab = A + (size_t)(m0 + w * 8 + (lane >> 3)) * K + gsw;
    const bf16* Bb = BT + (size_t)(n0 + w * 8 + (lane >> 3)) * K + gsw;

    for (int k0 = 0; k0 < K; k0 += 64) {
        #pragma unroll
        for (int p = 0; p < 4; p++)
            async16(Ab + (size_t)(p * 32) * K + k0, &As[p * 32 + w * 8][0]);
        #pragma unroll
        for (int p = 0; p < BN / 32; p++)
            async16(Bb + (size_t)(p * 32) * K + k0, &Bs[p * 32 + w * 8][0]);
        __syncthreads();
        #pragma unroll
        for (int ks = 0; ks < 2; ks++) {
            bf16x8 af[4], bfr[JF];
            int phys = (((4 * ks + lkg) ^ (lrow & 7)) << 3);
            #pragma unroll
            for (int i = 0; i < 4; i++) af[i] = *(const bf16x8*)&As[wm + i * 16 + lrow][phys];
            #pragma unroll
            for (int j = 0; j < JF; j++) bfr[j] = *(const bf16x8*)&Bs[wn + j * 16 + lrow][phys];
            #pragma unroll
            for (int i = 0; i < 4; i++)
                #pragma unroll
                for (int j = 0; j < JF; j++)
                    acc[i][j] = __builtin_amdgcn_mfma_f32_16x16x32_bf16(af[i], bfr[j], acc[i][j], 0, 0, 0);
        }
        __syncthreads();
    }

    int rgrp = (lane >> 4) * 4;
    #pragma unroll
    for (int i = 0; i < 4; i++) {
        #pragma unroll
        for (int j = 0; j < JF; j++) {
            int col = n0 + wn + j * 16 + lrow;
            int row0 = m0 + wm + i * 16 + rgrp;
            if (mode == 0) {
                if (col < 2048) {
                    float bb = aux[col];
                    if (col < 1024) bb *= QSCALE;
                    #pragma unroll
                    for (int reg = 0; reg < 4; reg++)
                        ((bf16*)Cout)[(size_t)(row0 + reg) * 2048 + col] = (bf16)(acc[i][j][reg] + bb);
                } else {
                    int c = col - 2048;
                    Pack4 p4;
                    #pragma unroll
                    for (int reg = 0; reg < 4; reg++) p4.h[reg] = (bf16)acc[i][j][reg];
                    *(uint2*)&C2T[(size_t)c * 4096 + row0] = p4.u2;
                }
            } else {
                #pragma unroll
                for (int reg = 0; reg < 4; reg++)
                    ((float*)Cout)[(size_t)(row0 + reg) * N + col] = acc[i][j][reg];
            }
        }
    }

    // V-blocks: 32-row column sums -> transposed csum[col][chunk] atomics
    if (mode == 0 && n0 >= 2048) {
        int chunkb = (m0 + wm) >> 5;
        #pragma unroll
        for (int j = 0; j < JF; j++) {
            float s0 = 0.f, s1 = 0.f;
            #pragma unroll
            for (int reg = 0; reg < 4; reg++) {
                s0 += acc[0][j][reg] + acc[1][j][reg];
                s1 += acc[2][j][reg] + acc[3][j][reg];
            }
            s0 += __shfl_xor(s0, 16, 64); s0 += __shfl_xor(s0, 32, 64);
            s1 += __shfl_xor(s1, 16, 64); s1 += __shfl_xor(s1, 32, 64);
            if (lkg == 0) {
                int col = n0 - 2048 + wn + j * 16 + lrow;
                atomicAdd(&csum[(size_t)col * 128 + chunkb], s0);
                atomicAdd(&csum[(size_t)col * 128 + chunkb + 1], s1);
            }
        }
    }
}

// ---------------- flash split-K, fixed-base softmax, diag/non-diag split ----------------
// v7: v4's dispatch + inner body (proven 47.6us, F=46MB compulsory), but TWO 64-k-tiles
// per barrier period with 4 LDS tile-buffers (64KB). Barrier count halves; the
// prefetch->consume window doubles (~1400cy compute > ~900cy HBM-miss latency), so
// staged loads land before the next __syncthreads drain. Skip granularity stays 64.
// nloc is always even (2(qt+1)-8ck), so exact tile-pairing. 2 blocks/CU cap
// (measured avg residency was 1.6 anyway).
__global__ __launch_bounds__(256, 2)
void flash_split(const bf16* __restrict__ qk, const bf16* __restrict__ vT,
                 bf16* __restrict__ Opart, float* __restrict__ lbuf,
                 int S, int E, int H) {
    __shared__ __align__(16) bf16 smem[32768];   // 64 KB: 4 x (Ks[64][64] | Vt[64][64])
    #define KS(bu, r, c) smem[(bu) * 8192 + (r) * 64 + (c)]
    #define VT(bu, r, c) smem[(bu) * 8192 + 4096 + (r) * 64 + (c)]

    int item = blockIdx.x, bh = blockIdx.y;
    int qt = QT_OF[item], ck = CK_OF[item];
    int b = bh >> 4, h = bh & 15;
    int q0 = qt * 128;
    int ktstart = ck * 8;
    int nloc = min(8, 2 * (qt + 1) - ktstart);   // always even, >= 2
    int t = threadIdx.x, lane = t & 63, w = t >> 6;
    int lrow = lane & 15, lkg = lane >> 4;
    const int ld = 2 * E;

    const bf16* Qg  = qk + (size_t)(b * S + q0) * ld + h * 64;
    const bf16* Kg0 = qk + (size_t)(b * S) * ld + E + h * 64;
    const bf16* Vg0 = vT + (size_t)(h * 64) * 4096 + b * 2048;

    bf16x8 qf[2][2];
    #pragma unroll
    for (int qg = 0; qg < 2; qg++)
        #pragma unroll
        for (int ks = 0; ks < 2; ks++)
            qf[qg][ks] = *(const bf16x8*)&Qg[(size_t)(32 * w + 16 * qg + lrow) * ld + ks * 32 + lkg * 8];

    f32x4 oacc[4][2] = {};
    float lrun[2] = {0.f, 0.f};

    auto stage = [&](int buf, int kt) {
        int k0 = kt * 64;
        int gg = (lane & 7) ^ ((lane >> 3) & 7);
        #pragma unroll
        for (int p = 0; p < 2; p++) {
            int row = w * 8 + p * 32 + (lane >> 3);
            async16(Kg0 + (size_t)(k0 + row) * ld + gg * 8, &KS(buf, row, (lane & 7) * 8));
        }
        // V: pi-permuted 4B-granule staging; LDS dest linear in lane, src carries sigma.
        int gcol = lane & 31;
        #pragma unroll
        for (int it = 0; it < 8; it++) {
            int row = it * 8 + w * 2 + (lane >> 5);
            int lb = (gcol >> 2) ^ (row & 7);                 // logical 16B block
            int kk = ((lb >> 2) << 5) | (((gcol >> 1) & 1) << 4)
                   | ((lb & 3) << 2) | ((gcol & 1) << 1);     // sigma(p): global k of granule
            async4(Vg0 + (size_t)row * 4096 + k0 + kk, &VT(buf, row, gcol * 2));
        }
    };

    // one 64-k-tile: QK^T -> register softmax -> PV  (identical to v4's body)
    auto compute = [&](int buf, int k0) {
        bool skip0 = (k0 > q0 + 32 * w + 15);
        bool skip1 = (k0 > q0 + 32 * w + 31);
        if (skip0 && skip1) return;

        f32x4 sacc[2][4] = {};
        #pragma unroll
        for (int ks = 0; ks < 2; ks++) {
            bf16x8 ak[4];
            int phys = (((4 * ks + lkg) ^ (lrow & 7)) << 3);
            #pragma unroll
            for (int kf = 0; kf < 4; kf++)
                ak[kf] = *(const bf16x8*)&KS(buf, 16 * kf + lrow, phys);
            #pragma unroll
            for (int kf = 0; kf < 4; kf++)
                sacc[0][kf] = __builtin_amdgcn_mfma_f32_16x16x32_bf16(ak[kf], qf[0][ks], sacc[0][kf], 0, 0, 0);
            if (!skip1)
                #pragma unroll
                for (int kf = 0; kf < 4; kf++)
                    sacc[1][kf] = __builtin_amdgcn_mfma_f32_16x16x32_bf16(ak[kf], qf[1][ks], sacc[1][kf], 0, 0, 0);
        }

        bf16x8 bp[2][2];
        #pragma unroll
        for (int qg = 0; qg < 2; qg++) {
            if ((qg == 0 && skip0) || (qg == 1 && skip1)) continue;
            int kmin = q0 + 32 * w + 16 * qg;
            float rs[4];
            if (k0 + 63 <= kmin) {
                #pragma unroll
                for (int kf = 0; kf < 4; kf++) {
                    float p[4];
                    #pragma unroll
                    for (int r = 0; r < 4; r++) {
                        p[r] = exp2f(sacc[qg][kf][r]);
                        bp[qg][kf >> 1][(kf & 1) * 4 + r] = (bf16)p[r];
                    }
                    rs[kf] = (p[0] + p[1]) + (p[2] + p[3]);
                }
            } else {
                int qrow = kmin + lrow;
                #pragma unroll
                for (int kf = 0; kf < 4; kf++) {
                    float p[4];
                    #pragma unroll
                    for (int r = 0; r < 4; r++) {
                        float sv = sacc[qg][kf][r];
                        if (k0 + 16 * kf + 4 * lkg + r > qrow) sv = -1e30f;
                        p[r] = exp2f(sv);
                        bp[qg][kf >> 1][(kf & 1) * 4 + r] = (bf16)p[r];
                    }
                    rs[kf] = (p[0] + p[1]) + (p[2] + p[3]);
                }
            }
            lrun[qg] += (rs[0] + rs[1]) + (rs[2] + rs[3]);
        }

        #pragma unroll
        for (int ks = 0; ks < 2; ks++) {
            bf16x8 av[4];
            int phys = (((4 * ks + lkg) ^ (lrow & 7)) << 3);
            #pragma unroll
            for (int df = 0; df < 4; df++)
                av[df] = *(const bf16x8*)&VT(buf, 16 * df + lrow, phys);
            #pragma unroll
            for (int qg = 0; qg < 2; qg++) {
                if ((qg == 0 && skip0) || (qg == 1 && skip1)) continue;
                #pragma unroll
                for (int df = 0; df < 4; df++)
                    oacc[df][qg] = __builtin_amdgcn_mfma_f32_16x16x32_bf16(av[df], bp[qg][ks], oacc[df][qg], 0, 0, 0);
            }
        }
    };

    // prologue: first tile-pair in flight
    stage(0, ktstart);
    stage(1, ktstart + 1);

    int nper = nloc >> 1;
    for (int pp = 0; pp < nper; pp++) {
        __syncthreads();                         // staged pair landed; prev pair fully consumed
        int pb = (pp & 1) * 2;                   // current pair: bufs pb, pb+1
        if (pp + 1 < nper) {                     // prefetch next pair into the other bufs
            stage(pb ^ 2, ktstart + 2 * pp + 2);
            stage((pb ^ 2) + 1, ktstart + 2 * pp + 3);
        }
        compute(pb,     (ktstart + 2 * pp) * 64);
        compute(pb + 1, (ktstart + 2 * pp + 1) * 64);
    }

    // epilogue: stage O through the (now idle) smem at stride 72
    __syncthreads();
    bf16* eps = smem;   // [4][32][72] = 18432 B < 64 KB
    size_t ibase = (size_t)(bh * 40 + item) * 128;
    #pragma unroll
    for (int qg = 0; qg < 2; qg++) {
        #pragma unroll
        for (int df = 0; df < 4; df++) {
            Pack4 p4;
            #pragma unroll
            for (int r = 0; r < 4; r++) p4.h[r] = (bf16)oacc[df][qg][r];
            *(uint2*)&eps[(size_t)(w * 32 + 16 * qg + lrow) * 72 + 16 * df + 4 * lkg] = p4.u2;
        }
        float l = lrun[qg];
        l += __shfl_xor(l, 16, 64);
        l += __shfl_xor(l, 32, 64);
        if (lkg == 0) lbuf[ibase + w * 32 + qg * 16 + lrow] = l;
    }
    int r_l = lane >> 1, half = lane & 1;
    bf16* orow = Opart + (ibase + w * 32 + r_l) * 64 + 32 * half;
    #pragma unroll
    for (int c = 0; c < 4; c++)
        *(uint4*)&orow[8 * c] = *(const uint4*)&eps[(size_t)(w * 32 + r_l) * 72 + 32 * half + 8 * c];
    #undef KS
    #undef VT
}

// ---------------- fused merge + combine (vectorized csum scan, V from vT) ----------------
__global__ void merge_combine(const bf16* __restrict__ Opart, const float* __restrict__ lbuf,
                              const bf16* __restrict__ vT, const float* __restrict__ csum,
                              const float* __restrict__ gr, const float* __restrict__ gs,
                              const float* __restrict__ gc, bf16* __restrict__ ctx) {
    const int S = 2048, E = 1024;
    int qt = blockIdx.x, bh = blockIdx.y;
    int b = bh >> 4, h = bh & 15;
    int nc = (qt >> 2) + 1, base = BASE_OF[qt];
    int q0 = qt * 128;
    int t = threadIdx.x;

    __shared__ bf16 osm[128][66];

    // phase A: merge partials -> normalized O (bf16) in LDS
    {
        int r = t >> 1, dh = (t & 1) * 32;
        float L = 0.f;
        for (int c = 0; c < nc; c++)
            L += lbuf[(size_t)(bh * 40 + base + c) * 128 + r];
        float inv = 1.f / L;
        float o[32] = {};
        for (int c = 0; c < nc; c++) {
            const bf16* src = Opart + ((size_t)(bh * 40 + base + c) * 128 + r) * 64 + dh;
            #pragma unroll
            for (int g = 0; g < 4; g++) {
                U16x8 u; u.u = *(const uint4*)&src[g * 8];
                #pragma unroll
                for (int j = 0; j < 8; j++) o[g * 8 + j] += (float)u.h[j];
            }
        }
        #pragma unroll
        for (int j = 0; j < 32; j++) osm[r][dh + j] = (bf16)(o[j] * inv);
    }
    __syncthreads();

    // phase B: 256 threads = 64 cols x 4 sub-chunks of 32 rows; vectorized prefix
    {
        int c = t & 63, sc = t >> 6;
        int col = h * 64 + c;
        int row0 = q0 + sc * 32;
        float grh = gr[h], gsh = gs[h], gch = gc[h];
        int cend = qt * 4 + sc;      // 32-row chunks before this sub-chunk (0..63)
        const float4* cs4 = (const float4*)(csum + (size_t)col * 128 + b * 64);
        float run = 0.f;
        #pragma unroll
        for (int g = 0; g < 16; g++) {
            float4 f = cs4[g];
            int j = g * 4;
            run += (j + 0 < cend ? f.x : 0.f) + (j + 1 < cend ? f.y : 0.f)
                 + (j + 2 < cend ? f.z : 0.f) + (j + 3 < cend ? f.w : 0.f);
        }
        const bf16* vrow = vT + (size_t)col * 4096 + b * 2048 + row0;
        U16x8 vv[4];
        #pragma unroll
        for (int g = 0; g < 4; g++) vv[g].u = *(const uint4*)&vrow[g * 8];
        bf16* cp = ctx + ((size_t)(b * S + row0)) * E + col;
        #pragma unroll
        for (int i = 0; i < 32; i++) {
            float v = (float)vv[i >> 3].h[i & 7];
            run += v;
            // v_rcp_f32 instead of full-precision divide (absmax budget 0.0625 >> rcp err)
            float pm = run * __builtin_amdgcn_rcpf((float)(row0 + i + 1));
            cp[(size_t)i * E] = (bf16)(grh * (float)osm[sc * 32 + i][c] + gsh * v - gch * pm);
        }
    }
}

extern "C" void kernel_launch(void* const* d_in, const int* in_sizes, int n_in,
                              void* d_out, int out_size, void* d_ws, size_t ws_size,
                              hipStream_t stream) {
    const float* hs  = (const float*)d_in[0];
    const float* qkw = (const float*)d_in[1];
    const float* qkb = (const float*)d_in[2];
    const float* vw  = (const float*)d_in[3];
    const float* vrg = (const float*)d_in[4];
    const float* vsg = (const float*)d_in[5];
    const float* pw  = (const float*)d_in[6];
    const float* prg = (const float*)d_in[7];
    const float* psg = (const float*)d_in[8];
    const float* amr = (const float*)d_in[9];
    const float* ams = (const float*)d_in[10];
    const float* amc = (const float*)d_in[11];
    float* out = (float*)d_out;

    const int B = 2, S = 2048, E = 1024, H = 16, M = B * S;
    char* ws = (char*)d_ws;
    size_t off = 0;
    auto alloc = [&](size_t bytes) { void* p = ws + off; off += (bytes + 255) & ~255ull; return p; };
    bf16* hsb   = (bf16*)alloc((size_t)M * E * 2);
    bf16* qkvT  = (bf16*)alloc((size_t)3 * E * E * 2);
    bf16* pwT   = (bf16*)alloc((size_t)E * E * 2);
    bf16* qko   = (bf16*)alloc((size_t)M * 2 * E * 2);
    bf16* vT    = (bf16*)alloc((size_t)E * M * 2);
    float* csum = (float*)alloc((size_t)E * 128 * 4);   // transposed: [col][chunk32]
    bf16* ctxb  = (bf16*)alloc((size_t)M * E * 2);
    bf16* Opart = (bf16*)alloc((size_t)32 * 40 * 128 * 64 * 2);
    float* lbuf = (float*)alloc((size_t)32 * 40 * 128 * 4);

    prep<<<8200, 256, 0, stream>>>(hs, hsb, qkw, vw, pw, qkvT, pwT, csum, vrg, vsg, prg, psg);

    gemm_bt<128><<<32 * (3 * E / 128), 256, 0, stream>>>(
        hsb, qkvT, M, 3 * E, E, qko, vT, csum, 0, qkb);

    flash_split<<<dim3(40, 32), 256, 0, stream>>>(qko, vT, Opart, lbuf, S, E, H);
    merge_combine<<<dim3(16, 32), 256, 0, stream>>>(Opart, lbuf, vT, csum, amr, ams, amc, ctxb);

    gemm_bt<64><<<32 * (E / 64), 256, 0, stream>>>(
        ctxb, pwT, M, E, E, out, nullptr, nullptr, 2, nullptr);
}

// Round 8
// 193.544 us; speedup vs baseline: 1.0805x; 1.0805x over previous
//
#include <hip/hip_runtime.h>

typedef __bf16 bf16;
typedef __attribute__((ext_vector_type(8))) __bf16 bf16x8;
typedef __attribute__((ext_vector_type(4))) float f32x4;

union U16x8 { uint4 u; bf16 h[8]; };
union Pack4 { uint2 u2; bf16 h[4]; };

#define QSCALE 0.18033688011112042f   // log2(e)/sqrt(64)

__device__ __forceinline__ void async16(const bf16* g, bf16* l) {
    __builtin_amdgcn_global_load_lds((const __attribute__((address_space(1))) void*)g,
                                     (__attribute__((address_space(3))) void*)l, 16, 0, 0);
}
__device__ __forceinline__ void async4(const bf16* g, bf16* l) {
    __builtin_amdgcn_global_load_lds((const __attribute__((address_space(1))) void*)g,
                                     (__attribute__((address_space(3))) void*)l, 4, 0, 0);
}

// split-K item tables: 40 items per (b,h)
__device__ const int QT_OF[40] = {15,15,15,15,14,14,14,14,13,13,13,13,12,12,12,12,
                                  11,11,11,10,10,10,9,9,9,8,8,8,7,7,6,6,5,5,4,4,3,2,1,0};
__device__ const int CK_OF[40] = {0,1,2,3,0,1,2,3,0,1,2,3,0,1,2,3,
                                  0,1,2,0,1,2,0,1,2,0,1,2,0,1,0,1,0,1,0,1,0,0,0,0};
__device__ const int BASE_OF[16] = {39,38,37,36,34,32,30,28,25,22,19,16,12,8,4,0};

// tail-aware dispatch: 28 heavy (nloc=8) items per bh first (bh-clustered for L2
// temporal reuse), then 12 light items (nloc 6/6/6/6/4/4/4/4/2/2/2/2) as drain.
__device__ const int HV_IT[28] = {0,1,2,3,4,5,6,8,9,10,12,13,14,16,17,18,19,20,22,23,25,26,28,29,30,32,34,36};
__device__ const int LT_IT[12] = {7,21,31,37,11,24,33,38,15,27,35,39};

// ---------------- prep: csum zero + fp32->bf16 convert + 3 weight transposes ----------------
__global__ void prep(const float* __restrict__ hs, bf16* __restrict__ hsb,
                     const float* __restrict__ qkw, const float* __restrict__ vw,
                     const float* __restrict__ pw, bf16* __restrict__ qkvT,
                     bf16* __restrict__ pwT, float* __restrict__ csum,
                     const float* __restrict__ vrg, const float* __restrict__ vsg,
                     const float* __restrict__ prg, const float* __restrict__ psg) {
    const int K = 1024;
    int bx = blockIdx.x;
    if (bx < 8) {
        float4* p = (float4*)csum + (bx * 256 + threadIdx.x) * 16;
        #pragma unroll
        for (int i = 0; i < 16; i++) p[i] = make_float4(0.f, 0.f, 0.f, 0.f);
        return;
    }
    if (bx < 4104) {
        int i = ((bx - 8) * 256 + threadIdx.x) * 4;
        float4 f = *(const float4*)(hs + i);
        hsb[i + 0] = (bf16)f.x; hsb[i + 1] = (bf16)f.y;
        hsb[i + 2] = (bf16)f.z; hsb[i + 3] = (bf16)f.w;
        return;
    }
    int r = bx - 4104;
    int z = r < 2048 ? 0 : (r < 3072 ? 1 : 2);
    int q = z == 0 ? r : (z == 1 ? r - 2048 : r - 3072);
    int ntiles = z == 0 ? 64 : 32;
    int N = z == 0 ? 2048 : 1024;
    const float* W = z == 0 ? qkw : (z == 1 ? vw : pw);
    bf16* WT = z == 0 ? qkvT : (z == 1 ? qkvT + (size_t)2 * 1024 * 1024 : pwT);
    float g0 = z == 0 ? 1.f : (z == 1 ? vrg[0] : prg[0]);
    float g1 = z == 0 ? 0.f : (z == 1 ? vsg[0] : psg[0]);

    __shared__ float tile[32][33];
    int n0 = (q % ntiles) * 32, k0 = (q / ntiles) * 32;
    int tx = threadIdx.x & 31, ty = threadIdx.x >> 5;
    #pragma unroll
    for (int rr = 0; rr < 32; rr += 8)
        tile[ty + rr][tx] = W[(size_t)(k0 + ty + rr) * N + n0 + tx];
    __syncthreads();
    #pragma unroll
    for (int rr = 0; rr < 32; rr += 8) {
        int n = n0 + ty + rr, k = k0 + tx;
        float v = g0 * tile[tx][ty + rr] + ((n == k) ? g1 : 0.f);
        if (z == 0 && n < 1024) v *= QSCALE;
        WT[(size_t)n * K + k] = (bf16)v;
    }
}

// ---------------- bf16 MFMA GEMM, XCD-swizzled 1D grid: C = A @ BT^T ----------------
// mode 0: fused qk+v. col<2048 -> qko (bias); col>=2048 -> vT (scatter) + csumT atomics
// mode 2: out fp32 = acc (gains pre-folded)
template<int BN>
__global__ __launch_bounds__(256, 3)
void gemm_bt(const bf16* __restrict__ A, const bf16* __restrict__ BT,
             int M, int N, int K, void* __restrict__ Cout,
             bf16* __restrict__ C2T, float* __restrict__ csum,
             int mode, const float* __restrict__ aux) {
    __shared__ __align__(16) bf16 As[128][64];
    __shared__ __align__(16) bf16 Bs[BN][64];
    constexpr int JF = BN / 32;
    int bid = blockIdx.x;
    int g32 = bid & 31;
    int m0 = ((g32 & 7) * 4 + (g32 >> 3)) * 128;
    int n0 = (bid >> 5) * BN;
    int t = threadIdx.x, lane = t & 63, w = t >> 6;
    int wm = (w >> 1) * 64, wn = (w & 1) * (BN / 2);
    int lrow = lane & 15, lkg = lane >> 4;

    f32x4 acc[4][JF] = {};

    int gsw = ((lane & 7) ^ ((lane >> 3) & 7)) * 8;
    const bf16* Ab = A + (size_t)(m0 + w * 8 + (lane >> 3)) * K + gsw;
    const bf16* Bb = BT + (size_t)(n0 + w * 8 + (lane >> 3)) * K + gsw;

    for (int k0 = 0; k0 < K; k0 += 64) {
        #pragma unroll
        for (int p = 0; p < 4; p++)
            async16(Ab + (size_t)(p * 32) * K + k0, &As[p * 32 + w * 8][0]);
        #pragma unroll
        for (int p = 0; p < BN / 32; p++)
            async16(Bb + (size_t)(p * 32) * K + k0, &Bs[p * 32 + w * 8][0]);
        __syncthreads();
        #pragma unroll
        for (int ks = 0; ks < 2; ks++) {
            bf16x8 af[4], bfr[JF];
            int phys = (((4 * ks + lkg) ^ (lrow & 7)) << 3);
            #pragma unroll
            for (int i = 0; i < 4; i++) af[i] = *(const bf16x8*)&As[wm + i * 16 + lrow][phys];
            #pragma unroll
            for (int j = 0; j < JF; j++) bfr[j] = *(const bf16x8*)&Bs[wn + j * 16 + lrow][phys];
            #pragma unroll
            for (int i = 0; i < 4; i++)
                #pragma unroll
                for (int j = 0; j < JF; j++)
                    acc[i][j] = __builtin_amdgcn_mfma_f32_16x16x32_bf16(af[i], bfr[j], acc[i][j], 0, 0, 0);
        }
        __syncthreads();
    }

    int rgrp = (lane >> 4) * 4;
    #pragma unroll
    for (int i = 0; i < 4; i++) {
        #pragma unroll
        for (int j = 0; j < JF; j++) {
            int col = n0 + wn + j * 16 + lrow;
            int row0 = m0 + wm + i * 16 + rgrp;
            if (mode == 0) {
                if (col < 2048) {
                    float bb = aux[col];
                    if (col < 1024) bb *= QSCALE;
                    #pragma unroll
                    for (int reg = 0; reg < 4; reg++)
                        ((bf16*)Cout)[(size_t)(row0 + reg) * 2048 + col] = (bf16)(acc[i][j][reg] + bb);
                } else {
                    int c = col - 2048;
                    Pack4 p4;
                    #pragma unroll
                    for (int reg = 0; reg < 4; reg++) p4.h[reg] = (bf16)acc[i][j][reg];
                    *(uint2*)&C2T[(size_t)c * 4096 + row0] = p4.u2;
                }
            } else {
                #pragma unroll
                for (int reg = 0; reg < 4; reg++)
                    ((float*)Cout)[(size_t)(row0 + reg) * N + col] = acc[i][j][reg];
            }
        }
    }

    // V-blocks: 32-row column sums -> transposed csum[col][chunk] atomics
    if (mode == 0 && n0 >= 2048) {
        int chunkb = (m0 + wm) >> 5;
        #pragma unroll
        for (int j = 0; j < JF; j++) {
            float s0 = 0.f, s1 = 0.f;
            #pragma unroll
            for (int reg = 0; reg < 4; reg++) {
                s0 += acc[0][j][reg] + acc[1][j][reg];
                s1 += acc[2][j][reg] + acc[3][j][reg];
            }
            s0 += __shfl_xor(s0, 16, 64); s0 += __shfl_xor(s0, 32, 64);
            s1 += __shfl_xor(s1, 16, 64); s1 += __shfl_xor(s1, 32, 64);
            if (lkg == 0) {
                int col = n0 - 2048 + wn + j * 16 + lrow;
                atomicAdd(&csum[(size_t)col * 128 + chunkb], s0);
                atomicAdd(&csum[(size_t)col * 128 + chunkb + 1], s1);
            }
        }
    }
}

// ---------------- flash split-K, fixed-base softmax, diag/non-diag split ----------------
// v8: v4's proven structure (51200B LDS pad -> 3 blk/CU locality, 2-barrier loop)
// + VALU diet: native v_exp_f32 (1 inst vs libm sequence), MFMA row-sum (ones-A
// fragment replaces ~70 fadds + epilogue shfls), tail-aware heavy-first dispatch.
__global__ __launch_bounds__(256, 3)
void flash_split(const bf16* __restrict__ qk, const bf16* __restrict__ vT,
                 bf16* __restrict__ Opart, float* __restrict__ lbuf,
                 int S, int E, int H) {
    // 51200 B total (= round-0/4 LDS block). Active: first 16384 elems
    // (Ks[2][64][64] | Vt[2][64][64]); remainder is residency-capping pad.
    __shared__ __align__(16) bf16 smem[25600];
    #define KS(bu, r, c) smem[(bu) * 4096 + (r) * 64 + (c)]
    #define VT(bu, r, c) smem[8192 + (bu) * 4096 + (r) * 64 + (c)]

    int g = blockIdx.x;
    int item, bh;
    if (g < 896) { bh = g / 28; item = HV_IT[g % 28]; }
    else { int g2 = g - 896; bh = g2 / 12; item = LT_IT[g2 % 12]; }

    int qt = QT_OF[item], ck = CK_OF[item];
    int b = bh >> 4, h = bh & 15;
    int q0 = qt * 128;
    int ktstart = ck * 8;
    int nloc = min(8, 2 * (qt + 1) - ktstart);
    int t = threadIdx.x, lane = t & 63, w = t >> 6;
    int lrow = lane & 15, lkg = lane >> 4;
    const int ld = 2 * E;

    const bf16* Qg  = qk + (size_t)(b * S + q0) * ld + h * 64;
    const bf16* Kg0 = qk + (size_t)(b * S) * ld + E + h * 64;
    const bf16* Vg0 = vT + (size_t)(h * 64) * 4096 + b * 2048;

    bf16x8 qf[2][2];
    #pragma unroll
    for (int qg = 0; qg < 2; qg++)
        #pragma unroll
        for (int ks = 0; ks < 2; ks++)
            qf[qg][ks] = *(const bf16x8*)&Qg[(size_t)(32 * w + 16 * qg + lrow) * ld + ks * 32 + lkg * 8];

    const bf16 one = (bf16)1.0f;
    const bf16x8 vones = {one, one, one, one, one, one, one, one};

    f32x4 oacc[4][2] = {};
    f32x4 lacc[2] = {};   // MFMA row-sum accumulator: every lane's regs = rsum(q-row lane&15)

    auto stage = [&](int buf, int kt) {
        int k0 = kt * 64;
        int gg = (lane & 7) ^ ((lane >> 3) & 7);
        #pragma unroll
        for (int p = 0; p < 2; p++) {
            int row = w * 8 + p * 32 + (lane >> 3);
            async16(Kg0 + (size_t)(k0 + row) * ld + gg * 8, &KS(buf, row, (lane & 7) * 8));
        }
        // V: pi-permuted 4B-granule staging; LDS dest linear in lane, src carries sigma.
        int gcol = lane & 31;
        #pragma unroll
        for (int it = 0; it < 8; it++) {
            int row = it * 8 + w * 2 + (lane >> 5);
            int lb = (gcol >> 2) ^ (row & 7);                 // logical 16B block
            int kk = ((lb >> 2) << 5) | (((gcol >> 1) & 1) << 4)
                   | ((lb & 3) << 2) | ((gcol & 1) << 1);     // sigma(p): global k of granule
            async4(Vg0 + (size_t)row * 4096 + k0 + kk, &VT(buf, row, gcol * 2));
        }
    };

    stage(0, ktstart);
    for (int kl = 0; kl < nloc; kl++) {
        int buf = kl & 1;
        int k0 = (ktstart + kl) * 64;
        __syncthreads();
        if (kl + 1 < nloc) stage(1 - buf, ktstart + kl + 1);

        bool skip0 = (k0 > q0 + 32 * w + 15);
        bool skip1 = (k0 > q0 + 32 * w + 31);
        if (skip0 && skip1) continue;

        f32x4 sacc[2][4] = {};
        #pragma unroll
        for (int ks = 0; ks < 2; ks++) {
            bf16x8 ak[4];
            int phys = (((4 * ks + lkg) ^ (lrow & 7)) << 3);
            #pragma unroll
            for (int kf = 0; kf < 4; kf++)
                ak[kf] = *(const bf16x8*)&KS(buf, 16 * kf + lrow, phys);
            #pragma unroll
            for (int kf = 0; kf < 4; kf++)
                sacc[0][kf] = __builtin_amdgcn_mfma_f32_16x16x32_bf16(ak[kf], qf[0][ks], sacc[0][kf], 0, 0, 0);
            if (!skip1)
                #pragma unroll
                for (int kf = 0; kf < 4; kf++)
                    sacc[1][kf] = __builtin_amdgcn_mfma_f32_16x16x32_bf16(ak[kf], qf[1][ks], sacc[1][kf], 0, 0, 0);
        }

        // softmax: native v_exp_f32 + pack P into PV B-fragments (registers only).
        // Row-sum via MFMA with ones-A: lacc += ones^T . P  (replaces fadds + shfls).
        bf16x8 bp[2][2];
        #pragma unroll
        for (int qg = 0; qg < 2; qg++) {
            if ((qg == 0 && skip0) || (qg == 1 && skip1)) continue;
            int kmin = q0 + 32 * w + 16 * qg;
            if (k0 + 63 <= kmin) {
                #pragma unroll
                for (int kf = 0; kf < 4; kf++)
                    #pragma unroll
                    for (int r = 0; r < 4; r++)
                        bp[qg][kf >> 1][(kf & 1) * 4 + r] =
                            (bf16)__builtin_amdgcn_exp2f(sacc[qg][kf][r]);
            } else {
                int qrow = kmin + lrow;
                #pragma unroll
                for (int kf = 0; kf < 4; kf++)
                    #pragma unroll
                    for (int r = 0; r < 4; r++) {
                        float sv = sacc[qg][kf][r];
                        if (k0 + 16 * kf + 4 * lkg + r > qrow) sv = -1e30f;
                        bp[qg][kf >> 1][(kf & 1) * 4 + r] = (bf16)__builtin_amdgcn_exp2f(sv);
                    }
            }
            lacc[qg] = __builtin_amdgcn_mfma_f32_16x16x32_bf16(vones, bp[qg][0], lacc[qg], 0, 0, 0);
            lacc[qg] = __builtin_amdgcn_mfma_f32_16x16x32_bf16(vones, bp[qg][1], lacc[qg], 0, 0, 0);
        }

        #pragma unroll
        for (int ks = 0; ks < 2; ks++) {
            bf16x8 av[4];
            int phys = (((4 * ks + lkg) ^ (lrow & 7)) << 3);
            #pragma unroll
            for (int df = 0; df < 4; df++)
                av[df] = *(const bf16x8*)&VT(buf, 16 * df + lrow, phys);
            #pragma unroll
            for (int qg = 0; qg < 2; qg++) {
                if ((qg == 0 && skip0) || (qg == 1 && skip1)) continue;
                #pragma unroll
                for (int df = 0; df < 4; df++)
                    oacc[df][qg] = __builtin_amdgcn_mfma_f32_16x16x32_bf16(av[df], bp[qg][ks], oacc[df][qg], 0, 0, 0);
            }
        }
    }

    // epilogue: stage O through the (now idle) smem at stride 72
    __syncthreads();
    bf16* eps = smem;   // [4][32][72] = 18432 B
    size_t ibase = (size_t)(bh * 40 + item) * 128;
    #pragma unroll
    for (int qg = 0; qg < 2; qg++) {
        #pragma unroll
        for (int df = 0; df < 4; df++) {
            Pack4 p4;
            #pragma unroll
            for (int r = 0; r < 4; r++) p4.h[r] = (bf16)oacc[df][qg][r];
            *(uint2*)&eps[(size_t)(w * 32 + 16 * qg + lrow) * 72 + 16 * df + 4 * lkg] = p4.u2;
        }
        // lacc[qg][0]: every lane holds rsum for q-row (lane&15) — no shuffle needed
        if (lkg == 0) lbuf[ibase + w * 32 + qg * 16 + lrow] = lacc[qg][0];
    }
    int r_l = lane >> 1, half = lane & 1;
    bf16* orow = Opart + (ibase + w * 32 + r_l) * 64 + 32 * half;
    #pragma unroll
    for (int c = 0; c < 4; c++)
        *(uint4*)&orow[8 * c] = *(const uint4*)&eps[(size_t)(w * 32 + r_l) * 72 + 32 * half + 8 * c];
    #undef KS
    #undef VT
}

// ---------------- fused merge + combine (vectorized csum scan, V from vT) ----------------
__global__ void merge_combine(const bf16* __restrict__ Opart, const float* __restrict__ lbuf,
                              const bf16* __restrict__ vT, const float* __restrict__ csum,
                              const float* __restrict__ gr, const float* __restrict__ gs,
                              const float* __restrict__ gc, bf16* __restrict__ ctx) {
    const int S = 2048, E = 1024;
    int qt = blockIdx.x, bh = blockIdx.y;
    int b = bh >> 4, h = bh & 15;
    int nc = (qt >> 2) + 1, base = BASE_OF[qt];
    int q0 = qt * 128;
    int t = threadIdx.x;

    __shared__ bf16 osm[128][66];

    // phase A: merge partials -> normalized O (bf16) in LDS
    {
        int r = t >> 1, dh = (t & 1) * 32;
        float L = 0.f;
        for (int c = 0; c < nc; c++)
            L += lbuf[(size_t)(bh * 40 + base + c) * 128 + r];
        float inv = 1.f / L;
        float o[32] = {};
        for (int c = 0; c < nc; c++) {
            const bf16* src = Opart + ((size_t)(bh * 40 + base + c) * 128 + r) * 64 + dh;
            #pragma unroll
            for (int g = 0; g < 4; g++) {
                U16x8 u; u.u = *(const uint4*)&src[g * 8];
                #pragma unroll
                for (int j = 0; j < 8; j++) o[g * 8 + j] += (float)u.h[j];
            }
        }
        #pragma unroll
        for (int j = 0; j < 32; j++) osm[r][dh + j] = (bf16)(o[j] * inv);
    }
    __syncthreads();

    // phase B: 256 threads = 64 cols x 4 sub-chunks of 32 rows; vectorized prefix
    {
        int c = t & 63, sc = t >> 6;
        int col = h * 64 + c;
        int row0 = q0 + sc * 32;
        float grh = gr[h], gsh = gs[h], gch = gc[h];
        int cend = qt * 4 + sc;      // 32-row chunks before this sub-chunk (0..63)
        const float4* cs4 = (const float4*)(csum + (size_t)col * 128 + b * 64);
        float run = 0.f;
        #pragma unroll
        for (int g = 0; g < 16; g++) {
            float4 f = cs4[g];
            int j = g * 4;
            run += (j + 0 < cend ? f.x : 0.f) + (j + 1 < cend ? f.y : 0.f)
                 + (j + 2 < cend ? f.z : 0.f) + (j + 3 < cend ? f.w : 0.f);
        }
        const bf16* vrow = vT + (size_t)col * 4096 + b * 2048 + row0;
        U16x8 vv[4];
        #pragma unroll
        for (int g = 0; g < 4; g++) vv[g].u = *(const uint4*)&vrow[g * 8];
        bf16* cp = ctx + ((size_t)(b * S + row0)) * E + col;
        #pragma unroll
        for (int i = 0; i < 32; i++) {
            float v = (float)vv[i >> 3].h[i & 7];
            run += v;
            // v_rcp_f32 instead of full divide (absmax budget 0.0625 >> rcp err)
            float pm = run * __builtin_amdgcn_rcpf((float)(row0 + i + 1));
            cp[(size_t)i * E] = (bf16)(grh * (float)osm[sc * 32 + i][c] + gsh * v - gch * pm);
        }
    }
}

extern "C" void kernel_launch(void* const* d_in, const int* in_sizes, int n_in,
                              void* d_out, int out_size, void* d_ws, size_t ws_size,
                              hipStream_t stream) {
    const float* hs  = (const float*)d_in[0];
    const float* qkw = (const float*)d_in[1];
    const float* qkb = (const float*)d_in[2];
    const float* vw  = (const float*)d_in[3];
    const float* vrg = (const float*)d_in[4];
    const float* vsg = (const float*)d_in[5];
    const float* pw  = (const float*)d_in[6];
    const float* prg = (const float*)d_in[7];
    const float* psg = (const float*)d_in[8];
    const float* amr = (const float*)d_in[9];
    const float* ams = (const float*)d_in[10];
    const float* amc = (const float*)d_in[11];
    float* out = (float*)d_out;

    const int B = 2, S = 2048, E = 1024, H = 16, M = B * S;
    char* ws = (char*)d_ws;
    size_t off = 0;
    auto alloc = [&](size_t bytes) { void* p = ws + off; off += (bytes + 255) & ~255ull; return p; };
    bf16* hsb   = (bf16*)alloc((size_t)M * E * 2);
    bf16* qkvT  = (bf16*)alloc((size_t)3 * E * E * 2);
    bf16* pwT   = (bf16*)alloc((size_t)E * E * 2);
    bf16* qko   = (bf16*)alloc((size_t)M * 2 * E * 2);
    bf16* vT    = (bf16*)alloc((size_t)E * M * 2);
    float* csum = (float*)alloc((size_t)E * 128 * 4);   // transposed: [col][chunk32]
    bf16* ctxb  = (bf16*)alloc((size_t)M * E * 2);
    bf16* Opart = (bf16*)alloc((size_t)32 * 40 * 128 * 64 * 2);
    float* lbuf = (float*)alloc((size_t)32 * 40 * 128 * 4);

    prep<<<8200, 256, 0, stream>>>(hs, hsb, qkw, vw, pw, qkvT, pwT, csum, vrg, vsg, prg, psg);

    gemm_bt<128><<<32 * (3 * E / 128), 256, 0, stream>>>(
        hsb, qkvT, M, 3 * E, E, qko, vT, csum, 0, qkb);

    flash_split<<<1280, 256, 0, stream>>>(qko, vT, Opart, lbuf, S, E, H);
    merge_combine<<<dim3(16, 32), 256, 0, stream>>>(Opart, lbuf, vT, csum, amr, ams, amc, ctxb);

    gemm_bt<64><<<32 * (E / 64), 256, 0, stream>>>(
        ctxb, pwT, M, E, E, out, nullptr, nullptr, 2, nullptr);
}